// Round 7
// baseline (180.207 us; speedup 1.0000x reference)
//
#include <hip/hip_runtime.h>
#include <hip/hip_bf16.h>

// Problem constants
#define B_ 8
#define T_ 1024
#define E_ 768
#define H_ 12
#define DH_ 64
#define E3_ 2304
#define M_ (B_ * T_)           // 8192 rows
// SCALE * log2(e): p = exp2(s * 0.125 * 1.4426950408889634)
// Applied to Q in gemm288's epilogue, NOT in the attention kernel.
#define SCALE_LOG2E 0.18033688011112042f

typedef __attribute__((ext_vector_type(8))) short short8;
typedef __attribute__((ext_vector_type(4))) float float4_;
typedef __attribute__((ext_vector_type(16))) float f32x16;
typedef __attribute__((ext_vector_type(4))) unsigned short ushort4_;

__device__ __forceinline__ unsigned short f2bf(float f) {
    union { float f; unsigned int u; } v; v.f = f;
    unsigned int r = v.u + 0x7fffu + ((v.u >> 16) & 1u);
    return (unsigned short)(r >> 16);
}

// packed f32x2 -> bf16x2 (v_cvt_pk_bf16_f32, RNE — bit-identical to f2bf)
__device__ __forceinline__ unsigned int pk_bf16(float a, float b) {
    float2 t; t.x = a; t.y = b;
    union { __hip_bfloat162 h; unsigned int u; } cv;
    cv.h = __float22bfloat162_rn(t);
    return cv.u;
}

// v_permlane32_swap_b32: a.hi32lanes <-> b.lo32lanes (both regs updated):
// a' = {a[0:31], b[l-32]} ; b' = {a[l+32], b[32:63]}
__device__ __forceinline__ void pl32swap(unsigned int& a, unsigned int& b) {
    asm volatile("v_permlane32_swap_b32 %0, %1" : "+v"(a), "+v"(b));
}

// async global->LDS, 16B per lane. LDS dest must be wave-uniform base + lane*16.
__device__ __forceinline__ void gld_lds16(const unsigned short* g, unsigned short* l) {
    __builtin_amdgcn_global_load_lds(
        (const __attribute__((address_space(1))) void*)g,
        (__attribute__((address_space(3))) void*)l,
        16, 0, 0);
}

// ---------------------------------------------------------------------------
// prep: one kernel for all prepasses (unchanged).
// ---------------------------------------------------------------------------
__global__ __launch_bounds__(256) void prep(const float* __restrict__ hs,
                                            const float* __restrict__ qkv_w,
                                            const float* __restrict__ proj_w,
                                            unsigned short* __restrict__ hs_bf,
                                            unsigned short* __restrict__ qkvwT,
                                            unsigned short* __restrict__ projwT) {
    __shared__ float tile[32][33];
    const int id = blockIdx.x;
    const int tid = threadIdx.x;
    if (id < 6144) {
        const int i = (id * 256 + tid) * 4;
        float4_ v = *(const float4_*)(hs + i);
        ushort4_ o;
        o.x = f2bf(v.x); o.y = f2bf(v.y); o.z = f2bf(v.z); o.w = f2bf(v.w);
        *(ushort4_*)(hs_bf + i) = o;
        return;
    }
    const float* W; unsigned short* Wt; int N, bx, by;
    if (id < 6144 + 1728) {
        const int t = id - 6144; W = qkv_w; Wt = qkvwT; N = E3_;
        bx = t % 72; by = t / 72;
    } else {
        const int t = id - 7872; W = proj_w; Wt = projwT; N = E_;
        bx = t % 24; by = t / 24;
    }
    const int k0 = by * 32, n0 = bx * 32;
    const int tx = tid & 31, ty = tid >> 5;
    for (int i = ty; i < 32; i += 8)
        tile[i][tx] = W[(size_t)(k0 + i) * N + n0 + tx];
    __syncthreads();
    for (int i = ty; i < 32; i += 8)
        Wt[(size_t)(n0 + i) * E_ + k0 + tx] = f2bf(tile[tx][i]);
}

// ---------------------------------------------------------------------------
// OLD 128x128 2-phase GEMM: kept for the output projection (N=768; 384 blocks
// at 2 blocks/CU co-resident).
// ---------------------------------------------------------------------------
template <int STORE_MODE>
__global__ __launch_bounds__(256) void gemm_mfma(const unsigned short* __restrict__ A,
                                                 const unsigned short* __restrict__ Wt,
                                                 const float* __restrict__ bias,
                                                 void* __restrict__ Cout,
                                                 unsigned short* __restrict__ Vt,
                                                 int M, int N, int K) {
    __shared__ __align__(16) unsigned short Al[2][128 * 32];
    __shared__ __align__(16) unsigned short Wl[2][128 * 32];

    const int tid = threadIdx.x;
    const int lane = tid & 63;
    const int w = tid >> 6;

    const int id = blockIdx.x;
    const int xcd = id & 7;
    const int slot = id >> 3;
    const int bx = slot >> 3;
    const int by = xcd * 8 + (slot & 7);
    const int bm = by * 128;
    const int bn = bx * 128;

    const int wm = (w >> 1) * 64;
    const int wn = (w & 1) * 64;
    const int quad = lane >> 4;
    const int l16 = lane & 15;

    const int srow = w * 32 + (lane >> 2);
    const int schunk = (lane & 3) * 8;
    const int sbase = w * 32 * 32 + lane * 8;

    const unsigned short* ga = A + (size_t)(bm + srow) * K + schunk;
    const unsigned short* gw = Wt + (size_t)(bn + srow) * K + schunk;

    float4_ acc[4][4] = {};

    gld_lds16(ga, &Al[0][sbase]);
    gld_lds16(ga + (size_t)16 * K, &Al[0][sbase + 512]);
    gld_lds16(gw, &Wl[0][sbase]);
    gld_lds16(gw + (size_t)16 * K, &Wl[0][sbase + 512]);

    const int NI = K >> 5;
    for (int i = 0; i < NI; ++i) {
        const int cur = i & 1;
        __syncthreads();
        if (i + 1 < NI) {
            const unsigned short* ga2 = ga + (size_t)(i + 1) * 32;
            const unsigned short* gw2 = gw + (size_t)(i + 1) * 32;
            const int nxt = cur ^ 1;
            gld_lds16(ga2, &Al[nxt][sbase]);
            gld_lds16(ga2 + (size_t)16 * K, &Al[nxt][sbase + 512]);
            gld_lds16(gw2, &Wl[nxt][sbase]);
            gld_lds16(gw2 + (size_t)16 * K, &Wl[nxt][sbase + 512]);
        }
        short8 af[4], bf[4];
#pragma unroll
        for (int mt = 0; mt < 4; ++mt)
            af[mt] = *(const short8*)(&Al[cur][(wm + mt * 16 + l16) * 32 + quad * 8]);
#pragma unroll
        for (int nt = 0; nt < 4; ++nt)
            bf[nt] = *(const short8*)(&Wl[cur][(wn + nt * 16 + l16) * 32 + quad * 8]);
#pragma unroll
        for (int mt = 0; mt < 4; ++mt)
#pragma unroll
            for (int nt = 0; nt < 4; ++nt)
                acc[mt][nt] = __builtin_amdgcn_mfma_f32_16x16x32_bf16(af[mt], bf[nt],
                                                                      acc[mt][nt], 0, 0, 0);
    }

    {
#pragma unroll
        for (int nt = 0; nt < 4; ++nt) {
            const int col = bn + wn + nt * 16 + l16;
            const float bv = bias[col];
#pragma unroll
            for (int mt = 0; mt < 4; ++mt) {
#pragma unroll
                for (int i = 0; i < 4; ++i) {
                    const int row = bm + wm + mt * 16 + quad * 4 + i;
                    const float v = acc[mt][nt][i] + bv;
                    if (STORE_MODE >= 1)
                        ((unsigned short*)Cout)[(size_t)row * N + col] = f2bf(v);
                    else
                        ((float*)Cout)[(size_t)row * N + col] = v;
                }
            }
        }
    }
    (void)Vt;
}

// ---------------------------------------------------------------------------
// 256x288 3-phase GEMM for the QKV projection (unchanged from R3).
// Grid = 256 blocks = 1/CU, single dispatch round.
// ---------------------------------------------------------------------------
__global__ __launch_bounds__(512, 2) void gemm288(const unsigned short* __restrict__ A,
                                                  const unsigned short* __restrict__ Wt,
                                                  const float* __restrict__ bias,
                                                  unsigned short* __restrict__ mixedOut,
                                                  unsigned short* __restrict__ Vt) {
    const int K = 768;
    const int NT = 12;                 // K / 64
    __shared__ __align__(16) unsigned short lds[70144]; // A:2*16384 | B:2*18432 | scratch:512

    const int tid = threadIdx.x;
    const int lane = tid & 63;
    const int w = tid >> 6;            // 0..7
    const int quad = lane >> 4;
    const int l16 = lane & 15;
    const int wM = w >> 1;             // 0..3 (64-row slice)
    const int wN = w & 1;              // 0..1 (144-col slice)

    // grid 256 = 8 xcd * (8 bx * 4 byl), byl innermost
    const int id = blockIdx.x;
    const int xcd = id & 7;
    const int slot = id >> 3;          // 0..31
    const int bx = slot >> 2;          // 0..7
    const int byl = slot & 3;
    const int bm = (xcd * 4 + byl) * 256;
    const int bn = bx * 288;

    // ---- B granule ownership, sorted by nh third (wave-uniform) ----
    const int j4 = (w < 4) ? (w + 32) : 36;
    int kk0 = ((w % 18) / 6) * 64 + w;
    int kk1 = (((w + 8) % 18) / 6) * 64 + (w + 8);
    int kk2 = (((w + 16) % 18) / 6) * 64 + (w + 16);
    int kk3 = (((w + 24) % 18) / 6) * 64 + (w + 24);
    int kk4 = (j4 >= 36) ? (3 * 64 + 36) : (((j4 % 18) / 6) * 64 + j4);
#define CS_(a, b) { int _lo = min(a, b), _hi = max(a, b); a = _lo; b = _hi; }
    CS_(kk0, kk1) CS_(kk3, kk4) CS_(kk2, kk4) CS_(kk2, kk3) CS_(kk1, kk4)
    CS_(kk0, kk3) CS_(kk0, kk2) CS_(kk1, kk3) CS_(kk1, kk2)
#undef CS_
    const int b0 = kk0 & 63, b1 = kk1 & 63, b2 = kk2 & 63, b3 = kk3 & 63, b4 = kk4 & 63;

    // ---- staging constants ----
    const int srcrow = lane >> 3;                               // row within granule
    const int ssw = ((lane & 7) ^ (srcrow & 7)) << 3;           // swizzled src chunk (elems)
    const unsigned short* gaL = A + (size_t)(bm + srcrow) * K + ssw;
    const unsigned short* gbL = Wt + (size_t)(bn + srcrow) * K + ssw;
    unsigned short* ldsl = lds + lane * 8;

    // ---- fragment-read constants ----
    const int rsw0 = ((quad) ^ (l16 & 7)) << 3;                 // ks=0
    const int rsw1 = ((quad + 4) ^ (l16 & 7)) << 3;             // ks=1
    const unsigned short* rdA = lds + (wM * 64 + l16) * 64;
    const unsigned short* rdB = lds + 32768 + (wN * 144 + l16) * 64;

    short8 aF[4][2], bF[3][2];
    float4_ acc[4][9] = {};

#define STA_(aj, toff, bufA) gld_lds16(gaL + (size_t)(aj) * 6144 + (toff), (bufA) + (aj) * 512)
#define STB_(j, toff, bufB) { \
    const int _j = (j); \
    const unsigned short* _s = gbL + (size_t)(_j >= 36 ? 0 : _j) * 6144 + (toff); \
    unsigned short* _d = (_j >= 36) ? (ldsl + 69632) : ((bufB) + _j * 512); \
    gld_lds16(_s, _d); }

#define LDA_(buf) { \
    const unsigned short* _a = rdA + (buf) * 16384; \
    aF[0][0] = *(const short8*)(_a + rsw0);        aF[0][1] = *(const short8*)(_a + rsw1); \
    aF[1][0] = *(const short8*)(_a + 1024 + rsw0); aF[1][1] = *(const short8*)(_a + 1024 + rsw1); \
    aF[2][0] = *(const short8*)(_a + 2048 + rsw0); aF[2][1] = *(const short8*)(_a + 2048 + rsw1); \
    aF[3][0] = *(const short8*)(_a + 3072 + rsw0); aF[3][1] = *(const short8*)(_a + 3072 + rsw1); }

#define LDB_(buf, nh) { \
    const unsigned short* _b = rdB + (buf) * 18432 + (nh) * 3072; \
    bF[0][0] = *(const short8*)(_b + rsw0);        bF[0][1] = *(const short8*)(_b + rsw1); \
    bF[1][0] = *(const short8*)(_b + 1024 + rsw0); bF[1][1] = *(const short8*)(_b + 1024 + rsw1); \
    bF[2][0] = *(const short8*)(_b + 2048 + rsw0); bF[2][1] = *(const short8*)(_b + 2048 + rsw1); }

#define MMA_(nh) \
    __builtin_amdgcn_s_setprio(1); \
    _Pragma("unroll") for (int mt = 0; mt < 4; ++mt) \
    _Pragma("unroll") for (int nt = 0; nt < 3; ++nt) { \
        acc[mt][(nh) * 3 + nt] = __builtin_amdgcn_mfma_f32_16x16x32_bf16( \
            aF[mt][0], bF[nt][0], acc[mt][(nh) * 3 + nt], 0, 0, 0); \
        acc[mt][(nh) * 3 + nt] = __builtin_amdgcn_mfma_f32_16x16x32_bf16( \
            aF[mt][1], bF[nt][1], acc[mt][(nh) * 3 + nt], 0, 0, 0); } \
    __builtin_amdgcn_s_setprio(0);

#define BARRIER_ __builtin_amdgcn_s_barrier()
#define WLGKM0_ { asm volatile("s_waitcnt lgkmcnt(0)" ::: "memory"); __builtin_amdgcn_sched_barrier(0); }
#define WVM3_ asm volatile("s_waitcnt vmcnt(3)" ::: "memory")
#define WVM0_ asm volatile("s_waitcnt vmcnt(0)" ::: "memory")

    // ---- prologue: stage tile 0 (A first, then nh-sorted B; dummies last) ----
    {
        unsigned short* bufA = ldsl;            // buf0 A
        unsigned short* bufB = ldsl + 32768;    // buf0 B
        STA_(w, 0, bufA); STA_(w + 8, 0, bufA); STA_(w + 16, 0, bufA); STA_(w + 24, 0, bufA);
        STB_(b0, 0, bufB); STB_(b1, 0, bufB); STB_(b2, 0, bufB); STB_(b3, 0, bufB); STB_(b4, 0, bufB);
    }
    WVM3_; BARRIER_;

#pragma unroll 1
    for (int t = 0; t < NT - 1; ++t) {
        const int buf = t & 1;
        const int toff = (t + 1) * 64;
        unsigned short* bufA = ldsl + (buf ^ 1) * 16384;
        unsigned short* bufB = ldsl + 32768 + (buf ^ 1) * 18432;

        // phase 0 (nh=0)
        LDA_(buf); LDB_(buf, 0);
        STA_(w, toff, bufA); STA_(w + 8, toff, bufA); STA_(w + 16, toff, bufA);
        BARRIER_; WLGKM0_; MMA_(0);
        WVM3_; BARRIER_;
        // phase 1 (nh=1)
        LDB_(buf, 1);
        STA_(w + 24, toff, bufA); STB_(b0, toff, bufB); STB_(b1, toff, bufB);
        BARRIER_; WLGKM0_; MMA_(1);
        WVM3_; BARRIER_;
        // phase 2 (nh=2)
        LDB_(buf, 2);
        STB_(b2, toff, bufB); STB_(b3, toff, bufB); STB_(b4, toff, bufB);
        BARRIER_; WLGKM0_; MMA_(2);
        WVM3_; BARRIER_;
    }
    // ---- peeled last tile (t = NT-1 = 11, buf = 1): no stages ----
    {
        LDA_(1); LDB_(1, 0);
        BARRIER_; WLGKM0_; MMA_(0);
        WVM0_; BARRIER_;          // drain phase2(NT-2) stages before nh1/nh2 reads
        LDB_(1, 1);
        BARRIER_; WLGKM0_; MMA_(1);
        BARRIER_;
        LDB_(1, 2);
        BARRIER_; WLGKM0_; MMA_(2);
    }
#undef STA_
#undef STB_
#undef LDA_
#undef LDB_
#undef MMA_

    // ---- epilogue ----
    // row = bm + wM*64 + mt*16 + quad*4 + i ; col = bn + wN*144 + ntg*16 + l16
    const int bb = bm >> 10;
    const int tloc = (bm & 1023) + wM * 64;
#pragma unroll
    for (int ntg = 0; ntg < 9; ++ntg) {
        const int col = bn + wN * 144 + ntg * 16 + l16;
        const float bv = bias[col];
        if (col >= 1536) {
            // V -> Vt[(b*12+h)*64 + d][1024], transposed
            const int n = col - 1536;
            const int h = n >> 6, d = n & 63;
            const size_t vrow = (size_t)((bb * H_ + h) * 64 + d) * T_;
#pragma unroll
            for (int mt = 0; mt < 4; ++mt) {
                uint2 pk;
                pk.x = pk_bf16(acc[mt][ntg][0] + bv, acc[mt][ntg][1] + bv);
                pk.y = pk_bf16(acc[mt][ntg][2] + bv, acc[mt][ntg][3] + bv);
                *(uint2*)(Vt + vrow + tloc + mt * 16 + quad * 4) = pk;
            }
        } else {
            const float qs = (col < 768) ? SCALE_LOG2E : 1.0f;
#pragma unroll
            for (int mt = 0; mt < 4; ++mt) {
#pragma unroll
                for (int i = 0; i < 4; ++i) {
                    const int row = bm + wM * 64 + mt * 16 + quad * 4 + i;
                    mixedOut[(size_t)row * E3_ + col] = f2bf((acc[mt][ntg][i] + bv) * qs);
                }
            }
        }
    }
}

// ---------------------------------------------------------------------------
// MFMA flash attention v10: 32x32 MFMA shape + FULLY IN-REGISTER softmax
// (T12). R6 profile: LDS pipe + P LDS round-trip dominated the per-tile
// serial chain (12 of 36 LDS ops/tile + 2 lgkmcnt waits were the C->A
// P relayout). With mfma_f32_32x32x16_bf16, S^T = K·Q^T gives each lane
// P values at col q = lane&31 — the SAME q-row the PV A-operand needs, so
// the relayout is 16 v_cvt_pk_bf16_f32 + 8 v_permlane32_swap_b32 (VALU),
// zero LDS. Pl buffer gone (LDS 35.3 -> 16.6 KB).
//   S^T C-layout: key = kg*32 + (r&3)+8*(r>>2)+4*hi, q = l32 (m74/m101).
//   A-frag(kc): keys kg*32+kc*16+hi*8+j: swap(u0,u2), swap(u1,u3) of the
//   cvt_pk'd pairs delivers words k-ascending for BOTH lane halves.
//   Row-sum: per-lane scalar over own 16 keys/kg; combine with one
//   shfl_xor(32) at the end; redistribute inv per C-row via 16 shfls.
// K/V LDS plane layouts and staging (incl. T14 prefetch) unchanged from R6.
// ---------------------------------------------------------------------------
__global__ __launch_bounds__(256) void attn_mfma(const unsigned short* __restrict__ mixed,
                                                 const unsigned short* __restrict__ Vt,
                                                 unsigned short* __restrict__ ctx) {
    const int bh = blockIdx.x;
    const int b = bh / H_;
    const int h = bh % H_;
    const int q0 = blockIdx.y * 128;
    const int tid = threadIdx.x;
    const int lane = tid & 63;
    const int w = tid >> 6;
    const int l32 = lane & 31;
    const int hi = lane >> 5;        // 0/1

    // K planes: plane p = d-chunk (8 d each): [64 keys][8 d], stride 520
    __shared__ __align__(16) unsigned short Kl[8 * 520];
    // V planes: plane = key-chunk (8 keys): [64 d][8 keys], stride 520
    __shared__ __align__(16) unsigned short Vl[8 * 520];

    // Q B-frags: B[d][q]: q-col = l32, d = dc*16 + hi*8 + j  (Q pre-scaled)
    short8 qB[4];
    {
        const size_t qrow = (size_t)(b * T_ + q0 + w * 32 + l32) * E3_ + h * 64;
#pragma unroll
        for (int dc = 0; dc < 4; ++dc)
            qB[dc] = *(const short8*)(mixed + qrow + dc * 16 + hi * 8);
    }

    f32x16 o0 = {};                  // O C-frag, d-block 0 (d = l32)
    f32x16 o1 = {};                  // O C-frag, d-block 1 (d = 32 + l32)
    float lps = 0.0f;                // per-lane row-sum partial (q = l32)

    const size_t kbase = (size_t)(b * T_) * E3_ + E_ + h * 64;
    const size_t vtb = (size_t)bh * 64 * T_;

    // staging maps (slot s = tid and tid+256):
    const int srow = tid >> 3;       // K: key 0..31 (+32) | V: d 0..31 (+32)
    const int sc = tid & 7;          // 16B chunk within 128B row

    // ---- prologue: load tile 0 into registers ----
    short8 k1 = *(const short8*)(mixed + kbase + (size_t)srow * E3_ + sc * 8);
    short8 k2 = *(const short8*)(mixed + kbase + (size_t)(srow + 32) * E3_ + sc * 8);
    short8 v1 = *(const short8*)(Vt + vtb + (size_t)srow * T_ + sc * 8);
    short8 v2 = *(const short8*)(Vt + vtb + (size_t)(srow + 32) * T_ + sc * 8);

    for (int kv0 = 0; kv0 < T_; kv0 += 64) {
        __syncthreads();             // waves done reading previous K/V tiles
        *(short8*)(&Kl[sc * 520 + srow * 8]) = k1;
        *(short8*)(&Kl[sc * 520 + (srow + 32) * 8]) = k2;
        *(short8*)(&Vl[sc * 520 + srow * 8]) = v1;
        *(short8*)(&Vl[sc * 520 + (srow + 32) * 8]) = v2;
        __syncthreads();

        // prefetch next tile (T14; latency hidden under compute below)
        if (kv0 + 64 < T_) {
            const int kn = kv0 + 64;
            k1 = *(const short8*)(mixed + kbase + (size_t)(kn + srow) * E3_ + sc * 8);
            k2 = *(const short8*)(mixed + kbase + (size_t)(kn + srow + 32) * E3_ + sc * 8);
            v1 = *(const short8*)(Vt + vtb + (size_t)srow * T_ + kn + sc * 8);
            v2 = *(const short8*)(Vt + vtb + (size_t)(srow + 32) * T_ + kn + sc * 8);
        }

#pragma unroll
        for (int kg = 0; kg < 2; ++kg) {
            // K A-frags: A[key][d]: key-row = kg*32 + l32, d = dc*16 + hi*8 + j
            short8 kf0 = *(const short8*)(&Kl[(0 + hi) * 520 + (kg * 32 + l32) * 8]);
            short8 kf1 = *(const short8*)(&Kl[(2 + hi) * 520 + (kg * 32 + l32) * 8]);
            short8 kf2 = *(const short8*)(&Kl[(4 + hi) * 520 + (kg * 32 + l32) * 8]);
            short8 kf3 = *(const short8*)(&Kl[(6 + hi) * 520 + (kg * 32 + l32) * 8]);

            // S^T = K Q^T over d=64 (4 chained K=16 steps)
            f32x16 st = {};
            st = __builtin_amdgcn_mfma_f32_32x32x16_bf16(kf0, qB[0], st, 0, 0, 0);
            st = __builtin_amdgcn_mfma_f32_32x32x16_bf16(kf1, qB[1], st, 0, 0, 0);
            st = __builtin_amdgcn_mfma_f32_32x32x16_bf16(kf2, qB[2], st, 0, 0, 0);
            st = __builtin_amdgcn_mfma_f32_32x32x16_bf16(kf3, qB[3], st, 0, 0, 0);

            // p = exp2(s') (scale pre-folded into Q); per-lane row-sum
            float e[16];
#pragma unroll
            for (int r = 0; r < 16; ++r)
                e[r] = __builtin_amdgcn_exp2f(st[r]);
            lps += ((((e[0] + e[1]) + (e[2] + e[3])) + ((e[4] + e[5]) + (e[6] + e[7]))) +
                    (((e[8] + e[9]) + (e[10] + e[11])) + ((e[12] + e[13]) + (e[14] + e[15]))));

            // P C->A relayout fully in registers: cvt_pk + permlane32_swap
            unsigned int u0 = pk_bf16(e[0], e[1]);
            unsigned int u1 = pk_bf16(e[2], e[3]);
            unsigned int u2 = pk_bf16(e[4], e[5]);
            unsigned int u3 = pk_bf16(e[6], e[7]);
            pl32swap(u0, u2);
            pl32swap(u1, u3);
            unsigned int u4 = pk_bf16(e[8], e[9]);
            unsigned int u5 = pk_bf16(e[10], e[11]);
            unsigned int u6 = pk_bf16(e[12], e[13]);
            unsigned int u7 = pk_bf16(e[14], e[15]);
            pl32swap(u4, u6);
            pl32swap(u5, u7);
            union { unsigned int u[4]; short8 s; } pa0, pa1;
            pa0.u[0] = u0; pa0.u[1] = u1; pa0.u[2] = u2; pa0.u[3] = u3;  // keys kg*32+kc0
            pa1.u[0] = u4; pa1.u[1] = u5; pa1.u[2] = u6; pa1.u[3] = u7;  // keys kg*32+16

            // V B-frags: B[key][d]: d-col = nb*32 + l32, keys plane-contig
            short8 vb00 = *(const short8*)(&Vl[(kg * 4 + 0 + hi) * 520 + l32 * 8]);
            short8 vb01 = *(const short8*)(&Vl[(kg * 4 + 0 + hi) * 520 + (32 + l32) * 8]);
            short8 vb10 = *(const short8*)(&Vl[(kg * 4 + 2 + hi) * 520 + l32 * 8]);
            short8 vb11 = *(const short8*)(&Vl[(kg * 4 + 2 + hi) * 520 + (32 + l32) * 8]);

            // O += P V
            o0 = __builtin_amdgcn_mfma_f32_32x32x16_bf16(pa0.s, vb00, o0, 0, 0, 0);
            o1 = __builtin_amdgcn_mfma_f32_32x32x16_bf16(pa0.s, vb01, o1, 0, 0, 0);
            o0 = __builtin_amdgcn_mfma_f32_32x32x16_bf16(pa1.s, vb10, o0, 0, 0, 0);
            o1 = __builtin_amdgcn_mfma_f32_32x32x16_bf16(pa1.s, vb11, o1, 0, 0, 0);
        }
    }

    // finalize: combine the two half-lane partials (each covers 16/32 keys
    // per kg for q = l32), then redistribute 1/l to the C-layout rows.
    const float lt = lps + __shfl_xor(lps, 32, 64);
    const float invq = 1.0f / lt;    // valid at q = l32 (both lane halves)
#pragma unroll
    for (int r = 0; r < 16; ++r) {
        const int row = (r & 3) + 8 * (r >> 2) + 4 * hi;   // q-row of this reg
        const float iv = __shfl(invq, row, 32);
        const size_t orow = (size_t)(b * T_ + q0 + w * 32 + row) * E_ + h * 64 + l32;
        ctx[orow] = f2bf(o0[r] * iv);
        ctx[orow + 32] = f2bf(o1[r] * iv);
    }
}

// ---------------------------------------------------------------------------
extern "C" void kernel_launch(void* const* d_in, const int* in_sizes, int n_in,
                              void* d_out, int out_size, void* d_ws, size_t ws_size,
                              hipStream_t stream) {
    const float* hs     = (const float*)d_in[0];
    const float* qkv_w  = (const float*)d_in[1];
    const float* qkv_b  = (const float*)d_in[2];
    const float* proj_w = (const float*)d_in[3];
    const float* proj_b = (const float*)d_in[4];
    float* out = (float*)d_out;

    unsigned short* hs_bf  = (unsigned short*)d_ws;                 // [8192][768]
    unsigned short* qkvwT  = hs_bf + (size_t)M_ * E_;               // [2304][768]
    unsigned short* projwT = qkvwT + (size_t)E3_ * E_;              // [768][768]
    unsigned short* mixed  = projwT + (size_t)E_ * E_;              // [8192][2304]
    unsigned short* Vt     = mixed + (size_t)M_ * E3_;              // [96*64][1024]
    unsigned short* ctx    = hs_bf;  // alias: hs_bf dead after GEMM1

    // 0) fused prepasses: cast + both weight transposes
    prep<<<8448, 256, 0, stream>>>(hs, qkv_w, proj_w, hs_bf, qkvwT, projwT);

    // 1) QKV projection -> mixed (Q scaled, K bf16) + Vt (V transposed)
    gemm288<<<256, 512, 0, stream>>>(hs_bf, qkvwT, qkv_b, mixed, Vt);
    // 2) attention -> ctx (bf16)  [32x32 MFMA, in-register softmax]
    attn_mfma<<<dim3(B_ * H_, T_ / 128), 256, 0, stream>>>(mixed, Vt, ctx);
    // 3) output projection -> out (fp32), old 128x128 structure
    gemm_mfma<0><<<(E_ / 128) * (M_ / 128), 256, 0, stream>>>(ctx, projwT, proj_b,
                                                              (void*)out, nullptr, M_, E_, E_);
}

// Round 8
// 176.611 us; speedup vs baseline: 1.0204x; 1.0204x over previous
//
#include <hip/hip_runtime.h>
#include <hip/hip_bf16.h>

// Problem constants
#define B_ 8
#define T_ 1024
#define E_ 768
#define H_ 12
#define DH_ 64
#define E3_ 2304
#define M_ (B_ * T_)           // 8192 rows
// SCALE * log2(e): p = exp2(s * 0.125 * 1.4426950408889634)
// Applied to Q in gemm288's epilogue, NOT in the attention kernel.
#define SCALE_LOG2E 0.18033688011112042f

typedef __attribute__((ext_vector_type(8))) short short8;
typedef __attribute__((ext_vector_type(4))) float float4_;
typedef __attribute__((ext_vector_type(4))) unsigned short ushort4_;

__device__ __forceinline__ unsigned short f2bf(float f) {
    union { float f; unsigned int u; } v; v.f = f;
    unsigned int r = v.u + 0x7fffu + ((v.u >> 16) & 1u);
    return (unsigned short)(r >> 16);
}

// packed f32x2 -> bf16x2 (v_cvt_pk_bf16_f32, RNE — bit-identical to f2bf)
__device__ __forceinline__ unsigned int pk_bf16(float a, float b) {
    float2 t; t.x = a; t.y = b;
    union { __hip_bfloat162 h; unsigned int u; } cv;
    cv.h = __float22bfloat162_rn(t);
    return cv.u;
}

// async global->LDS, 16B per lane. LDS dest must be wave-uniform base + lane*16.
__device__ __forceinline__ void gld_lds16(const unsigned short* g, unsigned short* l) {
    __builtin_amdgcn_global_load_lds(
        (const __attribute__((address_space(1))) void*)g,
        (__attribute__((address_space(3))) void*)l,
        16, 0, 0);
}

// ---------------------------------------------------------------------------
// prep: one kernel for all prepasses (unchanged).
// ---------------------------------------------------------------------------
__global__ __launch_bounds__(256) void prep(const float* __restrict__ hs,
                                            const float* __restrict__ qkv_w,
                                            const float* __restrict__ proj_w,
                                            unsigned short* __restrict__ hs_bf,
                                            unsigned short* __restrict__ qkvwT,
                                            unsigned short* __restrict__ projwT) {
    __shared__ float tile[32][33];
    const int id = blockIdx.x;
    const int tid = threadIdx.x;
    if (id < 6144) {
        const int i = (id * 256 + tid) * 4;
        float4_ v = *(const float4_*)(hs + i);
        ushort4_ o;
        o.x = f2bf(v.x); o.y = f2bf(v.y); o.z = f2bf(v.z); o.w = f2bf(v.w);
        *(ushort4_*)(hs_bf + i) = o;
        return;
    }
    const float* W; unsigned short* Wt; int N, bx, by;
    if (id < 6144 + 1728) {
        const int t = id - 6144; W = qkv_w; Wt = qkvwT; N = E3_;
        bx = t % 72; by = t / 72;
    } else {
        const int t = id - 7872; W = proj_w; Wt = projwT; N = E_;
        bx = t % 24; by = t / 24;
    }
    const int k0 = by * 32, n0 = bx * 32;
    const int tx = tid & 31, ty = tid >> 5;
    for (int i = ty; i < 32; i += 8)
        tile[i][tx] = W[(size_t)(k0 + i) * N + n0 + tx];
    __syncthreads();
    for (int i = ty; i < 32; i += 8)
        Wt[(size_t)(n0 + i) * E_ + k0 + tx] = f2bf(tile[tx][i]);
}

// ---------------------------------------------------------------------------
// 256x288 3-phase GEMM for the QKV projection (unchanged — proven, R2-R7).
// Grid = 256 blocks = 1/CU, single dispatch round.
// ---------------------------------------------------------------------------
__global__ __launch_bounds__(512, 2) void gemm288(const unsigned short* __restrict__ A,
                                                  const unsigned short* __restrict__ Wt,
                                                  const float* __restrict__ bias,
                                                  unsigned short* __restrict__ mixedOut,
                                                  unsigned short* __restrict__ Vt) {
    const int K = 768;
    const int NT = 12;                 // K / 64
    __shared__ __align__(16) unsigned short lds[70144]; // A:2*16384 | B:2*18432 | scratch:512

    const int tid = threadIdx.x;
    const int lane = tid & 63;
    const int w = tid >> 6;            // 0..7
    const int quad = lane >> 4;
    const int l16 = lane & 15;
    const int wM = w >> 1;             // 0..3 (64-row slice)
    const int wN = w & 1;              // 0..1 (144-col slice)

    // grid 256 = 8 xcd * (8 bx * 4 byl), byl innermost
    const int id = blockIdx.x;
    const int xcd = id & 7;
    const int slot = id >> 3;          // 0..31
    const int bx = slot >> 2;          // 0..7
    const int byl = slot & 3;
    const int bm = (xcd * 4 + byl) * 256;
    const int bn = bx * 288;

    // ---- B granule ownership, sorted by nh third (wave-uniform) ----
    const int j4 = (w < 4) ? (w + 32) : 36;
    int kk0 = ((w % 18) / 6) * 64 + w;
    int kk1 = (((w + 8) % 18) / 6) * 64 + (w + 8);
    int kk2 = (((w + 16) % 18) / 6) * 64 + (w + 16);
    int kk3 = (((w + 24) % 18) / 6) * 64 + (w + 24);
    int kk4 = (j4 >= 36) ? (3 * 64 + 36) : (((j4 % 18) / 6) * 64 + j4);
#define CS_(a, b) { int _lo = min(a, b), _hi = max(a, b); a = _lo; b = _hi; }
    CS_(kk0, kk1) CS_(kk3, kk4) CS_(kk2, kk4) CS_(kk2, kk3) CS_(kk1, kk4)
    CS_(kk0, kk3) CS_(kk0, kk2) CS_(kk1, kk3) CS_(kk1, kk2)
#undef CS_
    const int b0 = kk0 & 63, b1 = kk1 & 63, b2 = kk2 & 63, b3 = kk3 & 63, b4 = kk4 & 63;

    // ---- staging constants ----
    const int srcrow = lane >> 3;                               // row within granule
    const int ssw = ((lane & 7) ^ (srcrow & 7)) << 3;           // swizzled src chunk (elems)
    const unsigned short* gaL = A + (size_t)(bm + srcrow) * K + ssw;
    const unsigned short* gbL = Wt + (size_t)(bn + srcrow) * K + ssw;
    unsigned short* ldsl = lds + lane * 8;

    // ---- fragment-read constants ----
    const int rsw0 = ((quad) ^ (l16 & 7)) << 3;                 // ks=0
    const int rsw1 = ((quad + 4) ^ (l16 & 7)) << 3;             // ks=1
    const unsigned short* rdA = lds + (wM * 64 + l16) * 64;
    const unsigned short* rdB = lds + 32768 + (wN * 144 + l16) * 64;

    short8 aF[4][2], bF[3][2];
    float4_ acc[4][9] = {};

#define STA_(aj, toff, bufA) gld_lds16(gaL + (size_t)(aj) * 6144 + (toff), (bufA) + (aj) * 512)
#define STB_(j, toff, bufB) { \
    const int _j = (j); \
    const unsigned short* _s = gbL + (size_t)(_j >= 36 ? 0 : _j) * 6144 + (toff); \
    unsigned short* _d = (_j >= 36) ? (ldsl + 69632) : ((bufB) + _j * 512); \
    gld_lds16(_s, _d); }

#define LDA_(buf) { \
    const unsigned short* _a = rdA + (buf) * 16384; \
    aF[0][0] = *(const short8*)(_a + rsw0);        aF[0][1] = *(const short8*)(_a + rsw1); \
    aF[1][0] = *(const short8*)(_a + 1024 + rsw0); aF[1][1] = *(const short8*)(_a + 1024 + rsw1); \
    aF[2][0] = *(const short8*)(_a + 2048 + rsw0); aF[2][1] = *(const short8*)(_a + 2048 + rsw1); \
    aF[3][0] = *(const short8*)(_a + 3072 + rsw0); aF[3][1] = *(const short8*)(_a + 3072 + rsw1); }

#define LDB_(buf, nh) { \
    const unsigned short* _b = rdB + (buf) * 18432 + (nh) * 3072; \
    bF[0][0] = *(const short8*)(_b + rsw0);        bF[0][1] = *(const short8*)(_b + rsw1); \
    bF[1][0] = *(const short8*)(_b + 1024 + rsw0); bF[1][1] = *(const short8*)(_b + 1024 + rsw1); \
    bF[2][0] = *(const short8*)(_b + 2048 + rsw0); bF[2][1] = *(const short8*)(_b + 2048 + rsw1); }

#define MMA_(nh) \
    __builtin_amdgcn_s_setprio(1); \
    _Pragma("unroll") for (int mt = 0; mt < 4; ++mt) \
    _Pragma("unroll") for (int nt = 0; nt < 3; ++nt) { \
        acc[mt][(nh) * 3 + nt] = __builtin_amdgcn_mfma_f32_16x16x32_bf16( \
            aF[mt][0], bF[nt][0], acc[mt][(nh) * 3 + nt], 0, 0, 0); \
        acc[mt][(nh) * 3 + nt] = __builtin_amdgcn_mfma_f32_16x16x32_bf16( \
            aF[mt][1], bF[nt][1], acc[mt][(nh) * 3 + nt], 0, 0, 0); } \
    __builtin_amdgcn_s_setprio(0);

#define BARRIER_ __builtin_amdgcn_s_barrier()
#define WLGKM0_ { asm volatile("s_waitcnt lgkmcnt(0)" ::: "memory"); __builtin_amdgcn_sched_barrier(0); }
#define WVM3_ asm volatile("s_waitcnt vmcnt(3)" ::: "memory")
#define WVM0_ asm volatile("s_waitcnt vmcnt(0)" ::: "memory")

    // ---- prologue: stage tile 0 (A first, then nh-sorted B; dummies last) ----
    {
        unsigned short* bufA = ldsl;            // buf0 A
        unsigned short* bufB = ldsl + 32768;    // buf0 B
        STA_(w, 0, bufA); STA_(w + 8, 0, bufA); STA_(w + 16, 0, bufA); STA_(w + 24, 0, bufA);
        STB_(b0, 0, bufB); STB_(b1, 0, bufB); STB_(b2, 0, bufB); STB_(b3, 0, bufB); STB_(b4, 0, bufB);
    }
    WVM3_; BARRIER_;

#pragma unroll 1
    for (int t = 0; t < NT - 1; ++t) {
        const int buf = t & 1;
        const int toff = (t + 1) * 64;
        unsigned short* bufA = ldsl + (buf ^ 1) * 16384;
        unsigned short* bufB = ldsl + 32768 + (buf ^ 1) * 18432;

        // phase 0 (nh=0)
        LDA_(buf); LDB_(buf, 0);
        STA_(w, toff, bufA); STA_(w + 8, toff, bufA); STA_(w + 16, toff, bufA);
        BARRIER_; WLGKM0_; MMA_(0);
        WVM3_; BARRIER_;
        // phase 1 (nh=1)
        LDB_(buf, 1);
        STA_(w + 24, toff, bufA); STB_(b0, toff, bufB); STB_(b1, toff, bufB);
        BARRIER_; WLGKM0_; MMA_(1);
        WVM3_; BARRIER_;
        // phase 2 (nh=2)
        LDB_(buf, 2);
        STB_(b2, toff, bufB); STB_(b3, toff, bufB); STB_(b4, toff, bufB);
        BARRIER_; WLGKM0_; MMA_(2);
        WVM3_; BARRIER_;
    }
    // ---- peeled last tile (t = NT-1 = 11, buf = 1): no stages ----
    {
        LDA_(1); LDB_(1, 0);
        BARRIER_; WLGKM0_; MMA_(0);
        WVM0_; BARRIER_;          // drain phase2(NT-2) stages before nh1/nh2 reads
        LDB_(1, 1);
        BARRIER_; WLGKM0_; MMA_(1);
        BARRIER_;
        LDB_(1, 2);
        BARRIER_; WLGKM0_; MMA_(2);
    }
#undef STA_
#undef STB_
#undef LDA_
#undef LDB_
#undef MMA_

    // ---- epilogue ----
    // row = bm + wM*64 + mt*16 + quad*4 + i ; col = bn + wN*144 + ntg*16 + l16
    const int bb = bm >> 10;
    const int tloc = (bm & 1023) + wM * 64;
#pragma unroll
    for (int ntg = 0; ntg < 9; ++ntg) {
        const int col = bn + wN * 144 + ntg * 16 + l16;
        const float bv = bias[col];
        if (col >= 1536) {
            // V -> Vt[(b*12+h)*64 + d][1024], transposed
            const int n = col - 1536;
            const int h = n >> 6, d = n & 63;
            const size_t vrow = (size_t)((bb * H_ + h) * 64 + d) * T_;
#pragma unroll
            for (int mt = 0; mt < 4; ++mt) {
                uint2 pk;
                pk.x = pk_bf16(acc[mt][ntg][0] + bv, acc[mt][ntg][1] + bv);
                pk.y = pk_bf16(acc[mt][ntg][2] + bv, acc[mt][ntg][3] + bv);
                *(uint2*)(Vt + vrow + tloc + mt * 16 + quad * 4) = pk;
            }
        } else {
            const float qs = (col < 768) ? SCALE_LOG2E : 1.0f;
#pragma unroll
            for (int mt = 0; mt < 4; ++mt) {
#pragma unroll
                for (int i = 0; i < 4; ++i) {
                    const int row = bm + wM * 64 + mt * 16 + quad * 4 + i;
                    mixedOut[(size_t)row * E3_ + col] = f2bf((acc[mt][ntg][i] + bv) * qs);
                }
            }
        }
    }
}

// ---------------------------------------------------------------------------
// NEW proj96: output projection on the gemm288 skeleton.
// M=8192, N=768, K=768. Tile 256x96 -> grid = 32 x 8 = 256 blocks = 1/CU
// (replaces the 128^2 2-barrier kernel at 384 blocks = uneven 1.5/CU fill
// + vmcnt(0)-drained loop). 512 thr / 8 waves as 4M x 2N; wave tile 64x48;
// acc[4][3]. BK=64, NT=12. LDS: A 2x32KB | B 2x12KB | scratch = 89KB (1
// block/CU — grid is 1/CU anyway).
// Staging granule = 1KB (64 lanes x 16B). A tile = 32 granules (4/wave:
// j=w+8m); B tile = 12 granules (wave w owns j=w; w<4 also j=8+w; w>=4 pad
// with a dummy into scratch so every wave issues the same VMEM count).
// Schedule/tile: p0 {LDA, LDB nt0 | stage A w,w+8,w+16 | vmcnt(3)},
//                p1 {LDB nt1     | stage A w+24, B1, B2 | vmcnt(3)},
//                p2 {LDB nt2     | no stages            | vmcnt(0)}.
// Own-stream guarantee (per wave): items staged at phase X are drained by
// the wait at end of phase X+1 (p0's by p1's vmcnt(3); p1's by p2's
// vmcnt(0)) — so everything consumed at t+1.p0 (all A + any-nt B) has
// landed. B granules are consumed at t+1.p(nt>=0) — covered. Same logic
// class as gemm288 (race-free over R2-R7 runs). Tail tile is read-only:
// no barriers. K-accumulation order identical to the old proj kernel.
// ---------------------------------------------------------------------------
__global__ __launch_bounds__(512, 2) void proj96(const unsigned short* __restrict__ A,
                                                 const unsigned short* __restrict__ Wt,
                                                 const float* __restrict__ bias,
                                                 float* __restrict__ out) {
    const int K = 768;
    const int NT = 12;
    __shared__ __align__(16) unsigned short lds[45568]; // A:2*16384 | B:2*6144 | scratch:512

    const int tid = threadIdx.x;
    const int lane = tid & 63;
    const int w = tid >> 6;            // 0..7
    const int quad = lane >> 4;
    const int l16 = lane & 15;
    const int wM = w >> 1;             // 0..3 (64-row slice)
    const int wN = w & 1;              // 0..1 (48-col slice)

    // grid 256 = 8 xcd * (8 bx * 4 byl)
    const int id = blockIdx.x;
    const int xcd = id & 7;
    const int slot = id >> 3;
    const int bx = slot >> 2;          // 0..7  (N tile, 96 cols)
    const int byl = slot & 3;
    const int bm = (xcd * 4 + byl) * 256;
    const int bn = bx * 96;

    const int jB2 = (w < 4) ? (8 + w) : -1;   // second B granule (or dummy)

    // ---- staging constants ----
    const int srcrow = lane >> 3;
    const int ssw = ((lane & 7) ^ (srcrow & 7)) << 3;
    const unsigned short* gaL = A + (size_t)(bm + srcrow) * K + ssw;
    const unsigned short* gbL = Wt + (size_t)(bn + srcrow) * K + ssw;
    unsigned short* ldsl = lds + lane * 8;

    // ---- fragment-read constants ----
    const int rsw0 = ((quad) ^ (l16 & 7)) << 3;
    const int rsw1 = ((quad + 4) ^ (l16 & 7)) << 3;
    const unsigned short* rdA = lds + (wM * 64 + l16) * 64;
    const unsigned short* rdB = lds + 32768 + (wN * 48 + l16) * 64;

    short8 aF[4][2], bF[2];
    float4_ acc[4][3] = {};

#define PSTA(aj, toff, nb) gld_lds16(gaL + (size_t)(aj) * 6144 + (toff), \
                                     ldsl + (nb) * 16384 + (aj) * 512)
#define PSTB(j, toff, nb) { \
    const int _j = (j); \
    const unsigned short* _s = gbL + (size_t)(_j < 0 ? 0 : _j) * 6144 + (toff); \
    unsigned short* _d = (_j < 0) ? (ldsl + 45056) : (ldsl + 32768 + (nb) * 6144 + _j * 512); \
    gld_lds16(_s, _d); }
#define PLDA(buf) { \
    const unsigned short* _a = rdA + (buf) * 16384; \
    aF[0][0] = *(const short8*)(_a + rsw0);        aF[0][1] = *(const short8*)(_a + rsw1); \
    aF[1][0] = *(const short8*)(_a + 1024 + rsw0); aF[1][1] = *(const short8*)(_a + 1024 + rsw1); \
    aF[2][0] = *(const short8*)(_a + 2048 + rsw0); aF[2][1] = *(const short8*)(_a + 2048 + rsw1); \
    aF[3][0] = *(const short8*)(_a + 3072 + rsw0); aF[3][1] = *(const short8*)(_a + 3072 + rsw1); }
#define PLDB(buf, nt_) { \
    const unsigned short* _b = rdB + (buf) * 6144 + (nt_) * 1024; \
    bF[0] = *(const short8*)(_b + rsw0); \
    bF[1] = *(const short8*)(_b + rsw1); }
#define PMMA(nt_) \
    __builtin_amdgcn_s_setprio(1); \
    _Pragma("unroll") for (int mt = 0; mt < 4; ++mt) { \
        acc[mt][nt_] = __builtin_amdgcn_mfma_f32_16x16x32_bf16(aF[mt][0], bF[0], acc[mt][nt_], 0, 0, 0); \
        acc[mt][nt_] = __builtin_amdgcn_mfma_f32_16x16x32_bf16(aF[mt][1], bF[1], acc[mt][nt_], 0, 0, 0); } \
    __builtin_amdgcn_s_setprio(0);
#define PBAR __builtin_amdgcn_s_barrier()
#define PLGKM0 { asm volatile("s_waitcnt lgkmcnt(0)" ::: "memory"); __builtin_amdgcn_sched_barrier(0); }

    // ---- prologue: stage tile 0 (6 issues), full drain ----
    PSTA(w, 0, 0); PSTA(w + 8, 0, 0); PSTA(w + 16, 0, 0); PSTA(w + 24, 0, 0);
    PSTB(w, 0, 0); PSTB(jB2, 0, 0);
    asm volatile("s_waitcnt vmcnt(0)" ::: "memory");
    PBAR;

#pragma unroll 1
    for (int t = 0; t < NT - 1; ++t) {
        const int buf = t & 1;
        const int nb = buf ^ 1;
        const int toff = (t + 1) * 64;

        // phase 0 (nt=0)
        PLDA(buf); PLDB(buf, 0);
        PSTA(w, toff, nb); PSTA(w + 8, toff, nb); PSTA(w + 16, toff, nb);
        PBAR; PLGKM0; PMMA(0);
        asm volatile("s_waitcnt vmcnt(3)" ::: "memory"); PBAR;
        // phase 1 (nt=1)
        PLDB(buf, 1);
        PSTA(w + 24, toff, nb); PSTB(w, toff, nb); PSTB(jB2, toff, nb);
        PBAR; PLGKM0; PMMA(1);
        asm volatile("s_waitcnt vmcnt(3)" ::: "memory"); PBAR;
        // phase 2 (nt=2) — no stages; full drain so t+1.p0 reads are safe
        PLDB(buf, 2);
        PBAR; PLGKM0; PMMA(2);
        asm volatile("s_waitcnt vmcnt(0)" ::: "memory"); PBAR;
    }
    // ---- tail tile (buf 1): fully landed, read-only, no barriers ----
    {
        PLDA(1);
        PLDB(1, 0); PLGKM0; PMMA(0);
        PLDB(1, 1); PLGKM0; PMMA(1);
        PLDB(1, 2); PLGKM0; PMMA(2);
    }
#undef PSTA
#undef PSTB
#undef PLDA
#undef PLDB
#undef PMMA
#undef PBAR
#undef PLGKM0

    // ---- epilogue: fp32 out, bit-identical accumulation vs old proj ----
#pragma unroll
    for (int nt = 0; nt < 3; ++nt) {
        const int col = bn + wN * 48 + nt * 16 + l16;
        const float bv = bias[col];
#pragma unroll
        for (int mt = 0; mt < 4; ++mt) {
#pragma unroll
            for (int i = 0; i < 4; ++i) {
                const int row = bm + wM * 64 + mt * 16 + quad * 4 + i;
                out[(size_t)row * E_ + col] = acc[mt][nt][i] + bv;
            }
        }
    }
}

// ---------------------------------------------------------------------------
// MFMA flash attention — EXACT R6 version (measured 44.2 us). R7's 32x32
// in-register-softmax variant regressed to 48.0 (VALU/dep-chain cost >
// LDS savings; the 5.5M "conflicts" here are 2-way = throughput-free per
// m136). LDS-staged K/V, per-wave P round-trip, T14 register prefetch.
// ---------------------------------------------------------------------------
__global__ __launch_bounds__(256) void attn_mfma(const unsigned short* __restrict__ mixed,
                                                 const unsigned short* __restrict__ Vt,
                                                 unsigned short* __restrict__ ctx) {
    const int bh = blockIdx.x;
    const int b = bh / H_;
    const int h = bh % H_;
    const int q0 = blockIdx.y * 128;
    const int tid = threadIdx.x;
    const int lane = tid & 63;
    const int w = tid >> 6;
    const int quad = lane >> 4;
    const int l16 = lane & 15;

    __shared__ __align__(16) unsigned short Kl[8 * 520];
    __shared__ __align__(16) unsigned short Vl[8 * 520];
    __shared__ __align__(16) unsigned short Pl[4][32 * 72];
    unsigned short* pw = &Pl[w][0];

    short8 qf[2][2];
#pragma unroll
    for (int hh = 0; hh < 2; ++hh) {
        const size_t qrow = (size_t)(b * T_ + q0 + w * 32 + hh * 16 + l16) * E3_ + h * 64;
        qf[hh][0] = *(const short8*)(mixed + qrow + quad * 8);
        qf[hh][1] = *(const short8*)(mixed + qrow + 32 + quad * 8);
    }

    float4_ o[2][4] = {};
    float lps[2] = {0.0f, 0.0f};

    const size_t kbase = (size_t)(b * T_) * E3_ + E_ + h * 64;
    const size_t vtb = (size_t)bh * 64 * T_;

    const int srow = tid >> 3;
    const int sc = tid & 7;

    short8 k1 = *(const short8*)(mixed + kbase + (size_t)srow * E3_ + sc * 8);
    short8 k2 = *(const short8*)(mixed + kbase + (size_t)(srow + 32) * E3_ + sc * 8);
    short8 v1 = *(const short8*)(Vt + vtb + (size_t)srow * T_ + sc * 8);
    short8 v2 = *(const short8*)(Vt + vtb + (size_t)(srow + 32) * T_ + sc * 8);

    for (int kv0 = 0; kv0 < T_; kv0 += 64) {
        __syncthreads();
        *(short8*)(&Kl[sc * 520 + srow * 8]) = k1;
        *(short8*)(&Kl[sc * 520 + (srow + 32) * 8]) = k2;
        *(short8*)(&Vl[sc * 520 + srow * 8]) = v1;
        *(short8*)(&Vl[sc * 520 + (srow + 32) * 8]) = v2;
        __syncthreads();

        if (kv0 + 64 < T_) {
            const int kn = kv0 + 64;
            k1 = *(const short8*)(mixed + kbase + (size_t)(kn + srow) * E3_ + sc * 8);
            k2 = *(const short8*)(mixed + kbase + (size_t)(kn + srow + 32) * E3_ + sc * 8);
            v1 = *(const short8*)(Vt + vtb + (size_t)srow * T_ + kn + sc * 8);
            v2 = *(const short8*)(Vt + vtb + (size_t)(srow + 32) * T_ + kn + sc * 8);
        }

        float4_ st[2][4];
#pragma unroll
        for (int nt = 0; nt < 4; ++nt) {
            const int key = nt * 16 + l16;
            short8 kf0 = *(const short8*)(&Kl[quad * 520 + key * 8]);
            short8 kf1 = *(const short8*)(&Kl[(4 + quad) * 520 + key * 8]);
#pragma unroll
            for (int hh = 0; hh < 2; ++hh) {
                float4_ z = {};
                z = __builtin_amdgcn_mfma_f32_16x16x32_bf16(kf0, qf[hh][0], z, 0, 0, 0);
                st[hh][nt] = __builtin_amdgcn_mfma_f32_16x16x32_bf16(kf1, qf[hh][1], z, 0, 0, 0);
            }
        }

#pragma unroll
        for (int hh = 0; hh < 2; ++hh) {
#pragma unroll
            for (int nt = 0; nt < 4; ++nt) {
                const float p0 = __builtin_amdgcn_exp2f(st[hh][nt][0]);
                const float p1 = __builtin_amdgcn_exp2f(st[hh][nt][1]);
                const float p2 = __builtin_amdgcn_exp2f(st[hh][nt][2]);
                const float p3 = __builtin_amdgcn_exp2f(st[hh][nt][3]);
                uint2 pk;
                pk.x = pk_bf16(p0, p1);
                pk.y = pk_bf16(p2, p3);
                lps[hh] += (p0 + p1) + (p2 + p3);
                *(uint2*)(&pw[(hh * 16 + l16) * 72 + nt * 16 + quad * 4]) = pk;
            }
        }

        short8 pf[2][2];
#pragma unroll
        for (int hh = 0; hh < 2; ++hh) {
            pf[hh][0] = *(const short8*)(&pw[(hh * 16 + l16) * 72 + quad * 8]);
            pf[hh][1] = *(const short8*)(&pw[(hh * 16 + l16) * 72 + 32 + quad * 8]);
        }

#pragma unroll
        for (int dt = 0; dt < 4; ++dt) {
            const int d = dt * 16 + l16;
            short8 vf0 = *(const short8*)(&Vl[quad * 520 + d * 8]);
            short8 vf1 = *(const short8*)(&Vl[(4 + quad) * 520 + d * 8]);
#pragma unroll
            for (int hh = 0; hh < 2; ++hh) {
                o[hh][dt] = __builtin_amdgcn_mfma_f32_16x16x32_bf16(pf[hh][0], vf0, o[hh][dt], 0, 0, 0);
                o[hh][dt] = __builtin_amdgcn_mfma_f32_16x16x32_bf16(pf[hh][1], vf1, o[hh][dt], 0, 0, 0);
            }
        }
    }

#pragma unroll
    for (int hh = 0; hh < 2; ++hh) {
        float l = lps[hh];
        l += __shfl_xor(l, 16, 64);
        l += __shfl_xor(l, 32, 64);
        float4_ inv;
#pragma unroll
        for (int i = 0; i < 4; ++i)
            inv[i] = 1.0f / __shfl(l, quad * 4 + i, 16);
#pragma unroll
        for (int dt = 0; dt < 4; ++dt) {
#pragma unroll
            for (int i = 0; i < 4; ++i) {
                const float v = o[hh][dt][i] * inv[i];
                const size_t row = (size_t)(b * T_ + q0 + w * 32 + hh * 16 + quad * 4 + i);
                ctx[row * E_ + h * 64 + dt * 16 + l16] = f2bf(v);
            }
        }
    }
}

// ---------------------------------------------------------------------------
extern "C" void kernel_launch(void* const* d_in, const int* in_sizes, int n_in,
                              void* d_out, int out_size, void* d_ws, size_t ws_size,
                              hipStream_t stream) {
    const float* hs     = (const float*)d_in[0];
    const float* qkv_w  = (const float*)d_in[1];
    const float* qkv_b  = (const float*)d_in[2];
    const float* proj_w = (const float*)d_in[3];
    const float* proj_b = (const float*)d_in[4];
    float* out = (float*)d_out;

    unsigned short* hs_bf  = (unsigned short*)d_ws;                 // [8192][768]
    unsigned short* qkvwT  = hs_bf + (size_t)M_ * E_;               // [2304][768]
    unsigned short* projwT = qkvwT + (size_t)E3_ * E_;              // [768][768]
    unsigned short* mixed  = projwT + (size_t)E_ * E_;              // [8192][2304]
    unsigned short* Vt     = mixed + (size_t)M_ * E3_;              // [96*64][1024]
    unsigned short* ctx    = hs_bf;  // alias: hs_bf dead after GEMM1

    // 0) fused prepasses: cast + both weight transposes
    prep<<<8448, 256, 0, stream>>>(hs, qkv_w, proj_w, hs_bf, qkvwT, projwT);

    // 1) QKV projection -> mixed (Q scaled, K bf16) + Vt (V transposed)
    gemm288<<<256, 512, 0, stream>>>(hs_bf, qkvwT, qkv_b, mixed, Vt);
    // 2) attention -> ctx (bf16)  [R6 version, measured 44.2 us]
    attn_mfma<<<dim3(B_ * H_, T_ / 128), 256, 0, stream>>>(mixed, Vt, ctx);
    // 3) output projection -> out (fp32), NEW 256x96 exact-fill 3-phase
    proj96<<<256, 512, 0, stream>>>(ctx, projwT, proj_b, out);
}